// Round 13
// baseline (382.261 us; speedup 1.0000x reference)
//
#include <hip/hip_runtime.h>
#include <math.h>

#define PN 2048
#define PC 1024
#define PH 8
#define PD 128
#define PC3 3072

typedef __bf16 bf16x8 __attribute__((ext_vector_type(8)));
typedef float  f32x4  __attribute__((ext_vector_type(4)));
typedef short  s8v    __attribute__((ext_vector_type(8)));
typedef short  s4v    __attribute__((ext_vector_type(4)));

__device__ __forceinline__ short f2bf(float x) {
    unsigned u = __float_as_uint(x);
    unsigned r = (u + 0x7fffu + ((u >> 16) & 1u)) >> 16;
    return (short)r;
}
__device__ __forceinline__ float bf2f(short s) {
    return __uint_as_float(((unsigned)(unsigned short)s) << 16);
}

#define LDS_DMA(g, l) __builtin_amdgcn_global_load_lds( \
    (const __attribute__((address_space(1))) void*)(g), \
    (__attribute__((address_space(3))) void*)(l), 16, 0, 0)

template<int N> __device__ __forceinline__ void vmwait() {
    if constexpr (N == 0) asm volatile("s_waitcnt vmcnt(0)" ::: "memory");
    else if constexpr (N == 2) asm volatile("s_waitcnt vmcnt(2)" ::: "memory");
    else if constexpr (N == 3) asm volatile("s_waitcnt vmcnt(3)" ::: "memory");
    else if constexpr (N == 4) asm volatile("s_waitcnt vmcnt(4)" ::: "memory");
    else if constexpr (N == 6) asm volatile("s_waitcnt vmcnt(6)" ::: "memory");
    else if constexpr (N == 8) asm volatile("s_waitcnt vmcnt(8)" ::: "memory");
    else if constexpr (N == 9) asm volatile("s_waitcnt vmcnt(9)" ::: "memory");
}

// ---------------- GEMM body: C = alpha * A @ B^T (+bias) (+transposed bf16 acc) ----
// BK=64 tiles (16 MFMA per barrier pair), whole-tile dbuf, lookahead-1 counted vmcnt.
template<int BM, int BN, bool OBF16, bool BIAS, bool ACCT>
__device__ __forceinline__ void gemm_body(
    char* smem,
    const short* __restrict__ A, int lda,
    const short* __restrict__ B, int ldb,
    void* __restrict__ Cv, int ldc,
    int K, float alpha, const float* __restrict__ bias,
    const short* __restrict__ accT, int ldat, int bx, int by)
{
    constexpr int NI = BM / 32, NJ = BN / 32;
    constexpr int LPS = 2 * (BM / 64 + BN / 64);   // staging loads per 64-K tile
    short* As = (short*)smem;                      // 2 × BM×64 shorts
    short* Bs = (short*)(smem + 4 * BM * 64);      // 2 × BN×64 shorts
    const int tid = threadIdx.x;
    const int wave = tid >> 6, lane = tid & 63;
    const int lrow = tid >> 2;
    const int lcol = (tid & 3) * 8;
    const int row0 = by * BM, col0 = bx * BN;
    const short* Ag = A + (long)(row0 + lrow) * lda + lcol;
    const short* Bg = B + (long)(col0 + lrow) * ldb + lcol;
    const int wr = (wave >> 1) * (BM / 2), wc = (wave & 1) * (BN / 2);
    const int m16 = lane & 15, q4 = lane >> 4, q8 = q4 * 8;

    auto stage = [&](int buf, int kt) {
        short* Ad = As + buf * (BM * 64);
        short* Bd = Bs + buf * (BN * 64);
        LDS_DMA(Ag + kt, Ad + wave * 512);
        if (BM == 128) LDS_DMA(Ag + kt + 64 * (long)lda, Ad + 2048 + wave * 512);
        LDS_DMA(Bg + kt, Bd + wave * 512);
        if (BN == 128) LDS_DMA(Bg + kt + 64 * (long)ldb, Bd + 2048 + wave * 512);
        LDS_DMA(Ag + kt + 32, Ad + BM * 32 + wave * 512);
        if (BM == 128) LDS_DMA(Ag + kt + 32 + 64 * (long)lda,
                               Ad + BM * 32 + 2048 + wave * 512);
        LDS_DMA(Bg + kt + 32, Bd + BN * 32 + wave * 512);
        if (BN == 128) LDS_DMA(Bg + kt + 32 + 64 * (long)ldb,
                               Bd + BN * 32 + 2048 + wave * 512);
    };

    f32x4 acc[NI][NJ];
#pragma unroll
    for (int i = 0; i < NI; ++i)
#pragma unroll
        for (int j = 0; j < NJ; ++j) acc[i][j] = (f32x4){0.f, 0.f, 0.f, 0.f};

    const int ntiles = K >> 6;
    stage(0, 0);

    for (int ti = 0; ti < ntiles; ++ti) {
        if (ti + 1 < ntiles) {
            stage((ti + 1) & 1, (ti + 1) << 6);
            vmwait<LPS>();     // tile t complete; tile t+1's loads stay in flight
        } else {
            vmwait<0>();
        }
        __builtin_amdgcn_s_barrier();
        __builtin_amdgcn_sched_barrier(0);
        const short* Ab = As + (ti & 1) * (BM * 64);
        const short* Bb = Bs + (ti & 1) * (BN * 64);
        __builtin_amdgcn_s_setprio(1);
#pragma unroll
        for (int p = 0; p < 2; ++p) {
            bf16x8 a[NI], b[NJ];
#pragma unroll
            for (int i = 0; i < NI; ++i)
                a[i] = *(const bf16x8*)&Ab[p * BM * 32 + (wr + i * 16 + m16) * 32 + q8];
#pragma unroll
            for (int j = 0; j < NJ; ++j)
                b[j] = *(const bf16x8*)&Bb[p * BN * 32 + (wc + j * 16 + m16) * 32 + q8];
#pragma unroll
            for (int i = 0; i < NI; ++i)
#pragma unroll
                for (int j = 0; j < NJ; ++j)
                    acc[i][j] = __builtin_amdgcn_mfma_f32_16x16x32_bf16(a[i], b[j], acc[i][j], 0, 0, 0);
        }
        __builtin_amdgcn_s_setprio(0);
        __builtin_amdgcn_sched_barrier(0);
        __builtin_amdgcn_s_barrier();
    }

#pragma unroll
    for (int i = 0; i < NI; ++i) {
        const int r0 = row0 + wr + i * 16 + q4 * 4;
#pragma unroll
        for (int j = 0; j < NJ; ++j) {
            const int c = col0 + wc + j * 16 + m16;
            const float bv = BIAS ? bias[c] : 0.0f;
            s4v av;
            if (ACCT) av = *(const s4v*)&accT[(long)c * ldat + r0];
#pragma unroll
            for (int t = 0; t < 4; ++t) {
                float x = acc[i][j][t] * alpha + bv;
                if (ACCT) x += bf2f(av[t]);
                const long off = (long)(r0 + t) * ldc + c;
                if (OBF16) ((short*)Cv)[off] = f2bf(x);
                else       ((float*)Cv)[off] = x;
            }
        }
    }
}

// standalone GEMM wrapper (z-batched)
template<int BM, int BN, bool OBF16, bool BIAS, bool ACCT>
__global__ __launch_bounds__(256) void mfma_gemm_k(
    const short* __restrict__ A, int lda, long zsa,
    const short* __restrict__ B, int ldb, long zsb,
    void* __restrict__ Cv, int ldc, long zsc,
    int K, float alpha, const float* __restrict__ bias,
    const short* __restrict__ accT, int ldat)
{
    __shared__ char smem[4 * BM * 64 + 4 * BN * 64];
    const int z = blockIdx.z;
    void* Cz = OBF16 ? (void*)((short*)Cv + (long)z * zsc)
                     : (void*)((float*)Cv + (long)z * zsc);
    gemm_body<BM, BN, OBF16, BIAS, ACCT>(smem,
        A + (long)z * zsa, lda, B + (long)z * zsb, ldb,
        Cz, ldc, K, alpha, bias, accT, ldat, blockIdx.x, blockIdx.y);
}

// merged: QKV projections (z=0 cls full 3C, z=1 reg q,k only) + W1/W2 convert (z=2)
__global__ __launch_bounds__(256) void qkv_conv_k(
    const short* __restrict__ xbf, const short* __restrict__ Wbf,
    short* __restrict__ qkv,
    const float* __restrict__ W1, const float* __restrict__ W2,
    short* __restrict__ W1_bf, short* __restrict__ W2p_bf)
{
    __shared__ char smem[4 * 128 * 64 + 4 * 64 * 64];
    const int z = blockIdx.z;
    if (z == 2) {
        // W1 (1M float4) + W2 packed (1M float4), grid-stride over 768 blocks
        const long stride = 768L * 256;
        const long M = 1024 * 1024;
        for (long i = (long)(blockIdx.y * 48 + blockIdx.x) * 256 + threadIdx.x;
             i < 2 * M; i += stride) {
            if (i < M) {
                float4 v = ((const float4*)W1)[i];
                s4v o;
                o[0] = f2bf(v.x); o[1] = f2bf(v.y);
                o[2] = f2bf(v.z); o[3] = f2bf(v.w);
                ((s4v*)W1_bf)[i] = o;
            } else {
                const long j = i - M;
                float4 v = ((const float4*)W2)[j];
                s4v o;
                o[0] = f2bf(v.x); o[1] = f2bf(v.y);
                o[2] = f2bf(v.z); o[3] = f2bf(v.w);
                const int e = (int)(j << 2);
                const int d = e >> 12, c = e & 4095;
                const long pe = (c < 2048) ? ((long)d * 2048 + c)
                                           : ((long)(1024 + d) * 2048 + (c - 2048));
                ((s4v*)W2p_bf)[pe >> 2] = o;
            }
        }
        return;
    }
    if (z == 1 && blockIdx.x >= 32) return;        // v_reg is dead
    gemm_body<128, 64, true, false, false>(smem,
        xbf + (long)z * PN * PC, PC, Wbf + (long)z * PC3 * PC, PC,
        (void*)(qkv + (long)z * PN * PC3), PC3, PC, 1.0f,
        nullptr, nullptr, 0, blockIdx.x, blockIdx.y);
}

// ---------------- attention row-sum body (64 rows x 512 cols; 3-buf lookahead-2) ----
__device__ __forceinline__ void rowsum_body(char* smem,
    const short* __restrict__ qkv,
    const float* __restrict__ cls_score, const float* __restrict__ fg_score,
    float* __restrict__ l_g, int rb, int h, int zz)
{
    short* Qs  = (short*)smem;                       // 4 × 2048 shorts (16 KB)
    short* Kpb = (short*)(smem + 16384);             // 3 × 4096 shorts (24 KB)
    float* lsum = (float*)(smem + 16384 + 24576);    // [64][2]
    const int tid = threadIdx.x, wave = tid >> 6, lane = tid & 63;
    const int lrow = tid >> 2, lcol = (tid & 3) * 8;
    const int wr = (wave >> 1) * 32, wc = (wave & 1) * 64;
    const int m16 = lane & 15, q4 = lane >> 4, q8 = q4 * 8;
    const int row0 = rb * 64;
    const int side = zz >> 2, chunk = zz & 3;
    const float* sc_g = side ? fg_score : cls_score;
    const short* base = qkv + (long)side * PN * PC3 + h * PD;
    const short* Qg = base + (long)(row0 + lrow) * PC3 + lcol;
    const short* Kg = base + PC + lcol;

    auto stageK = [&](int buf, int step) {   // 2 loads per step
        const int ct = step >> 2, kc = step & 3;
        const long kr = (long)(chunk * 512 + ct * 128 + lrow);
        LDS_DMA(Kg + kr * PC3 + kc * 32, Kpb + buf * 4096 + wave * 512);
        LDS_DMA(Kg + (kr + 64) * PC3 + kc * 32, Kpb + buf * 4096 + 2048 + wave * 512);
    };

#pragma unroll
    for (int kc = 0; kc < 4; ++kc)
        LDS_DMA(Qg + kc * 32, Qs + kc * 2048 + wave * 512);
    stageK(0, 0);
    stageK(1, 1);

    bf16x8 a[2][4];
    float rs[2][4] = {};
    f32x4 acc[2][4];
#pragma unroll
    for (int i = 0; i < 2; ++i)
#pragma unroll
        for (int j = 0; j < 4; ++j) acc[i][j] = (f32x4){0.f, 0.f, 0.f, 0.f};

#pragma unroll
    for (int t = 0; t < 16; ++t) {
        const int ct = t >> 2, kc = t & 3;
        if (t <= 13) {
            stageK((t + 2) % 3, t + 2);
            vmwait<4>();       // stages t+1,t+2 in flight; stage t (and Q) done
        } else if (t == 14) {
            vmwait<2>();
        } else {
            vmwait<0>();
        }
        __builtin_amdgcn_s_barrier();
        __builtin_amdgcn_sched_barrier(0);
        if (t == 0) {
#pragma unroll
            for (int i = 0; i < 2; ++i)
#pragma unroll
                for (int k2 = 0; k2 < 4; ++k2)
                    a[i][k2] = *(const bf16x8*)&Qs[k2 * 2048 + (wr + i * 16 + m16) * 32 + q8];
        }
        bf16x8 b[4];
#pragma unroll
        for (int j = 0; j < 4; ++j)
            b[j] = *(const bf16x8*)&Kpb[(t % 3) * 4096 + (wc + j * 16 + m16) * 32 + q8];
        __builtin_amdgcn_s_setprio(1);
#pragma unroll
        for (int i = 0; i < 2; ++i)
#pragma unroll
            for (int j = 0; j < 4; ++j)
                acc[i][j] = __builtin_amdgcn_mfma_f32_16x16x32_bf16(a[i][kc], b[j], acc[i][j], 0, 0, 0);
        __builtin_amdgcn_s_setprio(0);
        if (kc == 3) {
            const int ctg = chunk * 4 + ct;
#pragma unroll
            for (int j = 0; j < 4; ++j) {
                const float s25 = 25.0f * sc_g[ctg * 128 + wc + j * 16 + m16];
#pragma unroll
                for (int i = 0; i < 2; ++i)
#pragma unroll
                    for (int tt = 0; tt < 4; ++tt)
                        rs[i][tt] += __expf(acc[i][j][tt] * s25);
            }
#pragma unroll
            for (int i = 0; i < 2; ++i)
#pragma unroll
                for (int j = 0; j < 4; ++j) acc[i][j] = (f32x4){0.f, 0.f, 0.f, 0.f};
        }
        __builtin_amdgcn_sched_barrier(0);
        __builtin_amdgcn_s_barrier();
    }

#pragma unroll
    for (int i = 0; i < 2; ++i)
#pragma unroll
        for (int tt = 0; tt < 4; ++tt) {
            float v = rs[i][tt];
            v += __shfl_xor(v, 1, 64); v += __shfl_xor(v, 2, 64);
            v += __shfl_xor(v, 4, 64); v += __shfl_xor(v, 8, 64);
            if (m16 == 0) lsum[(wr + i * 16 + q4 * 4 + tt) * 2 + (wave & 1)] = v;
        }
    __syncthreads();
    if (tid < 64)
        atomicAdd(&l_g[((long)side * PH + h) * PN + row0 + tid],
                  lsum[tid * 2] + lsum[tid * 2 + 1]);
}

// merged: rowsum (z<8, y<8) + sim_raw GEMM (z==8)
__global__ __launch_bounds__(256) void rowsum_simraw_k(
    const short* __restrict__ qkv,
    const float* __restrict__ cls_score, const float* __restrict__ fg_score,
    float* __restrict__ l_g,
    const short* __restrict__ Vn, short* __restrict__ sim_raw_bf)
{
    __shared__ char smem[49152];
    if (blockIdx.z < 8) {
        if (blockIdx.y >= PH) return;
        rowsum_body(smem, qkv, cls_score, fg_score, l_g,
                    blockIdx.x, blockIdx.y, blockIdx.z);
    } else {
        gemm_body<128, 64, true, false, false>(smem, Vn, PC, Vn, PC,
            (void*)sim_raw_bf, PN, PC, 0.125f, nullptr, nullptr, 0,
            blockIdx.x, blockIdx.y);
    }
}

// ---------------- attention kernel B: per-head attn tiles ----------------
__global__ __launch_bounds__(256) void attn_combine_k(
    const short* __restrict__ qkv,
    const float* __restrict__ cls_score, const float* __restrict__ fg_score,
    const float* __restrict__ l_g,
    short* __restrict__ attn8)
{
    __shared__ short Qp[4][4096];   // [128][32] panels (8 KB each)
    __shared__ short Kp[4][2048];   // [64][32] panels (4 KB each)
    const int tid = threadIdx.x, wave = tid >> 6, lane = tid & 63;
    const int lrow = tid >> 2, lcol = (tid & 3) * 8;
    const int wr = (wave >> 1) * 64, wc = (wave & 1) * 32;
    const int m16 = lane & 15, q4 = lane >> 4, q8 = q4 * 8;
    const int col0 = blockIdx.x * 64, row0 = blockIdx.y * 128, h = blockIdx.z;
    const long NN = (long)PN * PN;

    auto stage = [&](int buf, int step) {   // step 0..7: 3 loads
        const int s = step >> 2, kc = step & 3;
        const short* bq = qkv + (long)s * PN * PC3 + h * PD;
        const short* Qg = bq + (long)(row0 + lrow) * PC3 + kc * 32 + lcol;
        LDS_DMA(Qg, Qp[buf] + wave * 512);
        LDS_DMA(Qg + 64 * (long)PC3, Qp[buf] + 2048 + wave * 512);
        LDS_DMA(bq + PC + (long)(col0 + lrow) * PC3 + kc * 32 + lcol,
                Kp[buf] + wave * 512);
    };

    float rl[2][4];
#pragma unroll
    for (int s = 0; s < 2; ++s)
#pragma unroll
        for (int j = 0; j < 4; ++j)
            rl[s][j] = 0.5f / l_g[((long)s * PH + h) * PN + row0 + wr + j * 16 + m16];

    stage(0, 0);
    stage(1, 1);
    stage(2, 2);

    f32x4 acc[2][4], comb[2][4];
#pragma unroll
    for (int i = 0; i < 2; ++i)
#pragma unroll
        for (int j = 0; j < 4; ++j) acc[i][j] = (f32x4){0.f, 0.f, 0.f, 0.f};

#pragma unroll
    for (int t = 0; t < 8; ++t) {
        const int s = t >> 2, kc = t & 3;
        if (t <= 4) {
            stage((t + 3) & 3, t + 3);
            vmwait<9>();       // stages t+1..t+3 in flight; stage t complete
        } else if (t == 5) {
            vmwait<6>();
        } else if (t == 6) {
            vmwait<3>();
        } else {
            vmwait<0>();
        }
        __builtin_amdgcn_s_barrier();
        __builtin_amdgcn_sched_barrier(0);
        bf16x8 qf[4], kf[2];
#pragma unroll
        for (int j = 0; j < 4; ++j)
            qf[j] = *(const bf16x8*)&Qp[t & 3][(wr + j * 16 + m16) * 32 + q8];
#pragma unroll
        for (int i = 0; i < 2; ++i)
            kf[i] = *(const bf16x8*)&Kp[t & 3][(wc + i * 16 + m16) * 32 + q8];
        __builtin_amdgcn_s_setprio(1);
#pragma unroll
        for (int i = 0; i < 2; ++i)
#pragma unroll
            for (int j = 0; j < 4; ++j)
                acc[i][j] = __builtin_amdgcn_mfma_f32_16x16x32_bf16(kf[i], qf[j], acc[i][j], 0, 0, 0);
        __builtin_amdgcn_s_setprio(0);
        if (kc == 3) {
            const float* sc_g = s ? fg_score : cls_score;
#pragma unroll
            for (int i = 0; i < 2; ++i) {
                const f32x4 sc4 = *(const f32x4*)&sc_g[col0 + wc + i * 16 + q4 * 4];
#pragma unroll
                for (int j = 0; j < 4; ++j)
#pragma unroll
                    for (int tt = 0; tt < 4; ++tt) {
                        const float e = __expf(acc[i][j][tt] * (25.0f * sc4[tt])) * rl[s][j];
                        comb[i][j][tt] = s ? (comb[i][j][tt] + e) : e;
                        acc[i][j][tt] = 0.f;
                    }
            }
        }
        __builtin_amdgcn_sched_barrier(0);
        __builtin_amdgcn_s_barrier();
    }

#pragma unroll
    for (int j = 0; j < 4; ++j) {
        const long rb = (long)h * NN + (long)(row0 + wr + j * 16 + m16) * PN
                      + col0 + wc + q4 * 4;
#pragma unroll
        for (int i = 0; i < 2; ++i) {
            s4v o;
#pragma unroll
            for (int tt = 0; tt < 4; ++tt) o[tt] = f2bf(comb[i][j][tt]);
            *(s4v*)&attn8[rb + i * 16] = o;
        }
    }
}

// ---------------- reductions ----------------
__device__ __forceinline__ float wave_sum(float v) {
#pragma unroll
    for (int o = 32; o > 0; o >>= 1) v += __shfl_xor(v, o, 64);
    return v;
}
__device__ __forceinline__ float wave_max(float v) {
#pragma unroll
    for (int o = 32; o > 0; o >>= 1) v = fmaxf(v, __shfl_xor(v, o, 64));
    return v;
}
__device__ __forceinline__ float block_sum(float v, float* sm) {
    v = wave_sum(v);
    __syncthreads();
    if ((threadIdx.x & 63) == 0) sm[threadIdx.x >> 6] = v;
    __syncthreads();
    return sm[0] + sm[1] + sm[2] + sm[3];
}
__device__ __forceinline__ float block_max(float v, float* sm) {
    v = wave_max(v);
    __syncthreads();
    if ((threadIdx.x & 63) == 0) sm[threadIdx.x >> 6] = v;
    __syncthreads();
    return fmaxf(fmaxf(sm[0], sm[1]), fmaxf(sm[2], sm[3]));
}

// ---------------- sim_round2 body ----------------
__device__ __forceinline__ void simr2_body(char* smem,
    const short* __restrict__ attn8, const short* __restrict__ Sraw,
    short* __restrict__ Sout, int row)
{
    float* sm = (float*)smem;
    const long NN = (long)PN * PN;
    const long rowoff = (long)row * PN + threadIdx.x * 8;
    float v[8] = {0.f, 0.f, 0.f, 0.f, 0.f, 0.f, 0.f, 0.f};
#pragma unroll
    for (int h = 0; h < PH; ++h) {
        s8v a = *(const s8v*)&attn8[(long)h * NN + rowoff];
#pragma unroll
        for (int j = 0; j < 8; ++j) v[j] += bf2f(a[j]);
    }
    bool keep[8];
    {
        s8v raw = *(const s8v*)&Sraw[rowoff];
#pragma unroll
        for (int j = 0; j < 8; ++j) {
            v[j] *= 0.125f;
            keep[j] = bf2f(raw[j]) > 0.75f;
        }
    }
    float mx = -1e30f;
#pragma unroll
    for (int j = 0; j < 8; ++j) mx = fmaxf(mx, v[j]);
    mx = block_max(mx, sm);
    float sum = 0.f;
#pragma unroll
    for (int j = 0; j < 8; ++j) { v[j] = __expf(v[j] - mx); sum += v[j]; }
    sum = block_sum(sum, sm);
    const float inv = 1.0f / sum;
    float msum = 0.f;
#pragma unroll
    for (int j = 0; j < 8; ++j) { v[j] = keep[j] ? v[j] * inv : 0.f; msum += v[j]; }
    msum = block_sum(msum, sm);
    const float minv = 1.0f / msum;
    s8v o;
#pragma unroll
    for (int j = 0; j < 8; ++j) o[j] = f2bf(v[j] * minv);
    *(s8v*)&Sout[rowoff] = o;
}

// merged: PV GEMM (bid<512) + sim_round2 (bid>=512)
__global__ __launch_bounds__(256) void pv_simr2_k(
    const short* __restrict__ attn8, const short* __restrict__ vT,
    short* __restrict__ trans,
    const short* __restrict__ Sraw, short* __restrict__ Sout)
{
    __shared__ char smem[4 * 64 * 64 + 4 * 64 * 64];   // 32 KB
    const int bid = blockIdx.x;
    if (bid < 512) {
        const int inner = bid & 63, bx = inner & 1, by = inner >> 1, z = bid >> 6;
        gemm_body<64, 64, true, false, false>(smem,
            attn8 + (long)z * PN * PN, PN,
            vT + (long)z * PD * PN, PN,
            (void*)(trans + (long)z * PD), 2 * PC,
            PN, 1.0f, nullptr, nullptr, 0, bx, by);
    } else {
        simr2_body(smem, attn8, Sraw, Sout, bid - 512);
    }
}

// ---------------- fp32 -> bf16 convert: x_cls, x_reg, Wqc, Wqr only ----------------
__global__ __launch_bounds__(256) void f2bf4_k(
    const float* __restrict__ s0, const float* __restrict__ s1,
    const float* __restrict__ s2, const float* __restrict__ s3,
    short* __restrict__ dst)
{
    const int n0 = 512 * 1024, n1 = 512 * 1024, n2 = 768 * 1024;
    const int i = blockIdx.x * 256 + threadIdx.x;
    const float* src;
    int j = i;
    if (j < n0) src = s0;
    else { j -= n0; if (j < n1) src = s1;
    else { j -= n1; if (j < n2) src = s2;
    else { j -= n2; src = s3; } } }
    float4 v = ((const float4*)src)[j];
    s4v o;
    o[0] = f2bf(v.x); o[1] = f2bf(v.y); o[2] = f2bf(v.z); o[3] = f2bf(v.w);
    ((s4v*)dst)[i] = o;
}

// ---------------- transpose body ----------------
__device__ __forceinline__ void tr_body(char* smem,
    const short* __restrict__ src, int sld, short* __restrict__ dst, int dld,
    int bx, int by)
{
    short* tl = (short*)smem;   // [64][72]
    const int r0 = by * 64, c0 = bx * 64;
    const int tr = threadIdx.x >> 2;
    const int tc = (threadIdx.x & 3) * 16;
    const short* sp = src + (long)(r0 + tr) * sld + c0 + tc;
    s8v v0 = *(const s8v*)sp;
    s8v v1 = *(const s8v*)(sp + 8);
    *(s8v*)&tl[tr * 72 + tc] = v0;
    *(s8v*)&tl[tr * 72 + tc + 8] = v1;
    __syncthreads();
    s8v o0, o1;
#pragma unroll
    for (int k = 0; k < 8; ++k) {
        o0[k] = tl[(tc + k) * 72 + tr];
        o1[k] = tl[(tc + 8 + k) * 72 + tr];
    }
    short* dp = dst + (long)(c0 + tr) * dld + r0 + tc;
    *(s8v*)dp = o0;
    *(s8v*)(dp + 8) = o1;
}

// ---------------- norms body ----------------
__device__ __forceinline__ void norms_body(short* __restrict__ qkv,
    short* __restrict__ Vn, short* __restrict__ trans, int n, int which)
{
    const int t = threadIdx.x;
    if (which < 4) {
        short* p = qkv + (long)(which >> 1) * ((long)PN * PC3)
                 + (long)n * PC3 + (which & 1) * PC + t * 4;
        s4v v = *(s4v*)p;
        float f0 = bf2f(v[0]), f1 = bf2f(v[1]), f2 = bf2f(v[2]), f3 = bf2f(v[3]);
        float ss = f0 * f0 + f1 * f1 + f2 * f2 + f3 * f3;
        ss += __shfl_xor(ss, 16, 64); ss += __shfl_xor(ss, 8, 64);
        ss += __shfl_xor(ss, 4, 64);  ss += __shfl_xor(ss, 2, 64);
        ss += __shfl_xor(ss, 1, 64);
        const float rn = rsqrtf(ss);
        s4v o;
        o[0] = f2bf(f0 * rn); o[1] = f2bf(f1 * rn);
        o[2] = f2bf(f2 * rn); o[3] = f2bf(f3 * rn);
        *(s4v*)p = o;
    } else {
        const short* p = qkv + (long)n * PC3 + 2 * PC + t * 4;
        s4v v = *(const s4v*)p;
        float f0 = bf2f(v[0]), f1 = bf2f(v[1]), f2 = bf2f(v[2]), f3 = bf2f(v[3]);
        float ss = f0 * f0 + f1 * f1 + f2 * f2 + f3 * f3;
        ss += __shfl_xor(ss, 16, 64); ss += __shfl_xor(ss, 8, 64);
        ss += __shfl_xor(ss, 4, 64);  ss += __shfl_xor(ss, 2, 64);
        ss += __shfl_xor(ss, 1, 64);
        const float rn = rsqrtf(ss);
        s4v o;
        o[0] = f2bf(f0 * rn); o[1] = f2bf(f1 * rn);
        o[2] = f2bf(f2 * rn); o[3] = f2bf(f3 * rn);
        *(s4v*)(Vn + (long)n * PC + t * 4) = o;
        *(s4v*)(trans + (long)n * (2 * PC) + PC + t * 4) = v;
    }
}

// merged: norms (y<5) + v-transpose (y==5, x<512)
__global__ __launch_bounds__(256) void norms_tr_k(
    short* __restrict__ qkv, short* __restrict__ Vn,
    short* __restrict__ trans, short* __restrict__ vT)
{
    __shared__ char smem[64 * 72 * 2];
    if (blockIdx.y < 5) {
        norms_body(qkv, Vn, trans, blockIdx.x, blockIdx.y);
    } else {
        if (blockIdx.x >= 512) return;
        tr_body(smem, qkv + 2 * PC, PC3, vT, PN,
                blockIdx.x & 15, blockIdx.x >> 4);
    }
}

// ---------------- host ----------------
extern "C" void kernel_launch(void* const* d_in, const int* in_sizes, int n_in,
                              void* d_out, int out_size, void* d_ws, size_t ws_size,
                              hipStream_t stream)
{
    (void)in_sizes; (void)n_in; (void)out_size; (void)ws_size;
    const float* x_cls = (const float*)d_in[0];
    const float* x_reg = (const float*)d_in[1];
    const float* cls_score = (const float*)d_in[2];
    const float* fg_score = (const float*)d_in[3];
    const float* Wqc = (const float*)d_in[4];
    const float* Wqr = (const float*)d_in[5];
    const float* W1 = (const float*)d_in[6];
    const float* b1 = (const float*)d_in[7];
    const float* W2 = (const float*)d_in[8];
    const float* b2 = (const float*)d_in[9];
    float* out = (float*)d_out;

    // ---- workspace (MiB offsets), peak ~156.2 MiB ----
    char* w = (char*)d_ws;
    short* qkv_cls_bf = (short*)(w + ((size_t)0   << 20)); // 12 MiB [N,3C]
    short* qkv_reg_bf = (short*)(w + ((size_t)12  << 20)); // 12 MiB (adjacent)
    short* attn8      = (short*)(w + ((size_t)24  << 20)); // 64 MiB [8][N,N] bf16
    short* sim_bf     = (short*)(w + ((size_t)88  << 20)); // 8 MiB
    short* sim_raw_bf = (short*)(w + ((size_t)104 << 20)); // 8 MiB
    short* Vn         = (short*)(w + ((size_t)112 << 20)); // 4 MiB
    short* vT         = (short*)(w + ((size_t)116 << 20)); // 4 MiB [C,N]
    short* bf_all     = (short*)(w + ((size_t)120 << 20)); // 36 MiB contiguous:
    short* x_cls_bf   = bf_all;                            //  @120, 4 MiB (x_reg @124 adj)
    short* Wqc_bf     = (short*)(w + ((size_t)128 << 20)); //  6 MiB (Wqr @134 adj)
    short* W1_bf      = (short*)(w + ((size_t)140 << 20)); //  8 MiB
    short* W2p_bf     = (short*)(w + ((size_t)148 << 20)); //  8 MiB [2048,2048] packed
    float* l_g        = (float*)(w + ((size_t)156 << 20)); // 128 KiB [2][8][N]
    // overlays (after underlying dead):
    short* trans      = (short*)(w + ((size_t)120 << 20)); // 8 MiB over x_* (post-QKV)
    short* feat       = (short*)(w + ((size_t)24  << 20)); // 8 MiB over attn8[0] (post r2)
    short* UVt        = (short*)(w + ((size_t)32  << 20)); // 8 MiB over attn8[1]

    const long NN = (long)PN * PN;

    // ---- fp32 -> bf16: x_cls, x_reg, Wqc, Wqr (QKV inputs only) ----
    f2bf4_k<<<10240, 256, 0, stream>>>(x_cls, x_reg, Wqc, Wqr, bf_all);

    // ---- QKV projections (z=0,1; reg trimmed) + W1/W2 convert hidden in z=2 ----
    qkv_conv_k<<<dim3(48, 16, 3), 256, 0, stream>>>(
        x_cls_bf, Wqc_bf, qkv_cls_bf, W1, W2, W1_bf, W2p_bf);

    // ---- norms + v transpose (merged) ----
    norms_tr_k<<<dim3(PN, 6), 256, 0, stream>>>(qkv_cls_bf, Vn, trans, vT);

    // ---- attention row sums + sim_raw GEMM (merged) ----
    hipMemsetAsync(l_g, 0, (size_t)2 * PH * PN * sizeof(float), stream);
    rowsum_simraw_k<<<dim3(32, 16, 9), 256, 0, stream>>>(
        qkv_cls_bf, cls_score, fg_score, l_g, Vn, sim_raw_bf);

    // ---- per-head attn tiles ----
    attn_combine_k<<<dim3(32, 16, PH), 256, 0, stream>>>(
        qkv_cls_bf, cls_score, fg_score, l_g, attn8);

    // ---- x = attn @ v (z=8) + sim_round2 (merged) ----
    pv_simr2_k<<<2560, 256, 0, stream>>>(attn8, vT, trans, sim_raw_bf, sim_bf);

    // ---- feat = trans @ W1^T + b1 (bf16) ----
    mfma_gemm_k<128, 64, true, true, false><<<dim3(32, 16, 1), 256, 0, stream>>>(
        trans, 2 * PC, 0, W1_bf, 2 * PC, 0, feat, 2 * PC, 0, 2 * PC, 1.0f, b1,
        nullptr, 0);

    // ---- UVt = W2p @ feat^T : rows [0,1024)=U^T, [1024,2048)=V2^T ----
    mfma_gemm_k<128, 64, true, false, false><<<dim3(32, 16, 1), 256, 0, stream>>>(
        W2p_bf, 2 * PC, 0, feat, 2 * PC, 0, UVt, PN, 0, 2 * PC, 1.0f, nullptr,
        nullptr, 0);

    // ---- out = sim_bf @ (U^T)^T + V2 + b2 (64x64 tiles: 512 blocks, 2/CU) ----
    mfma_gemm_k<64, 64, false, true, true><<<dim3(16, 32, 1), 256, 0, stream>>>(
        sim_bf, PN, 0, UVt, PN, 0, out, PC, 0, PN, 1.0f, b2,
        UVt + (long)PC * PN, PN);
}

// Round 14
// 378.027 us; speedup vs baseline: 1.0112x; 1.0112x over previous
//
#include <hip/hip_runtime.h>
#include <math.h>

#define PN 2048
#define PC 1024
#define PH 8
#define PD 128
#define PC3 3072

typedef __bf16 bf16x8 __attribute__((ext_vector_type(8)));
typedef float  f32x4  __attribute__((ext_vector_type(4)));
typedef short  s8v    __attribute__((ext_vector_type(8)));
typedef short  s4v    __attribute__((ext_vector_type(4)));

__device__ __forceinline__ short f2bf(float x) {
    unsigned u = __float_as_uint(x);
    unsigned r = (u + 0x7fffu + ((u >> 16) & 1u)) >> 16;
    return (short)r;
}
__device__ __forceinline__ float bf2f(short s) {
    return __uint_as_float(((unsigned)(unsigned short)s) << 16);
}

#define LDS_DMA(g, l) __builtin_amdgcn_global_load_lds( \
    (const __attribute__((address_space(1))) void*)(g), \
    (__attribute__((address_space(3))) void*)(l), 16, 0, 0)

template<int N> __device__ __forceinline__ void vmwait() {
    if constexpr (N == 0) asm volatile("s_waitcnt vmcnt(0)" ::: "memory");
    else if constexpr (N == 2) asm volatile("s_waitcnt vmcnt(2)" ::: "memory");
    else if constexpr (N == 3) asm volatile("s_waitcnt vmcnt(3)" ::: "memory");
    else if constexpr (N == 4) asm volatile("s_waitcnt vmcnt(4)" ::: "memory");
    else if constexpr (N == 6) asm volatile("s_waitcnt vmcnt(6)" ::: "memory");
    else if constexpr (N == 8) asm volatile("s_waitcnt vmcnt(8)" ::: "memory");
    else if constexpr (N == 9) asm volatile("s_waitcnt vmcnt(9)" ::: "memory");
}

// ---------------- GEMM body: C = alpha * A @ B^T (+bias) (+transposed bf16 acc) ----
// BK=64 tiles (16 MFMA per barrier pair), whole-tile dbuf, lookahead-1 counted vmcnt.
template<int BM, int BN, bool OBF16, bool BIAS, bool ACCT>
__device__ __forceinline__ void gemm_body(
    char* smem,
    const short* __restrict__ A, int lda,
    const short* __restrict__ B, int ldb,
    void* __restrict__ Cv, int ldc,
    int K, float alpha, const float* __restrict__ bias,
    const short* __restrict__ accT, int ldat, int bx, int by)
{
    constexpr int NI = BM / 32, NJ = BN / 32;
    constexpr int LPS = 2 * (BM / 64 + BN / 64);   // staging loads per 64-K tile
    short* As = (short*)smem;                      // 2 × BM×64 shorts
    short* Bs = (short*)(smem + 4 * BM * 64);      // 2 × BN×64 shorts
    const int tid = threadIdx.x;
    const int wave = tid >> 6, lane = tid & 63;
    const int lrow = tid >> 2;
    const int lcol = (tid & 3) * 8;
    const int row0 = by * BM, col0 = bx * BN;
    const short* Ag = A + (long)(row0 + lrow) * lda + lcol;
    const short* Bg = B + (long)(col0 + lrow) * ldb + lcol;
    const int wr = (wave >> 1) * (BM / 2), wc = (wave & 1) * (BN / 2);
    const int m16 = lane & 15, q4 = lane >> 4, q8 = q4 * 8;

    auto stage = [&](int buf, int kt) {
        short* Ad = As + buf * (BM * 64);
        short* Bd = Bs + buf * (BN * 64);
        LDS_DMA(Ag + kt, Ad + wave * 512);
        if (BM == 128) LDS_DMA(Ag + kt + 64 * (long)lda, Ad + 2048 + wave * 512);
        LDS_DMA(Bg + kt, Bd + wave * 512);
        if (BN == 128) LDS_DMA(Bg + kt + 64 * (long)ldb, Bd + 2048 + wave * 512);
        LDS_DMA(Ag + kt + 32, Ad + BM * 32 + wave * 512);
        if (BM == 128) LDS_DMA(Ag + kt + 32 + 64 * (long)lda,
                               Ad + BM * 32 + 2048 + wave * 512);
        LDS_DMA(Bg + kt + 32, Bd + BN * 32 + wave * 512);
        if (BN == 128) LDS_DMA(Bg + kt + 32 + 64 * (long)ldb,
                               Bd + BN * 32 + 2048 + wave * 512);
    };

    f32x4 acc[NI][NJ];
#pragma unroll
    for (int i = 0; i < NI; ++i)
#pragma unroll
        for (int j = 0; j < NJ; ++j) acc[i][j] = (f32x4){0.f, 0.f, 0.f, 0.f};

    const int ntiles = K >> 6;
    stage(0, 0);

    for (int ti = 0; ti < ntiles; ++ti) {
        if (ti + 1 < ntiles) {
            stage((ti + 1) & 1, (ti + 1) << 6);
            vmwait<LPS>();     // tile t complete; tile t+1's loads stay in flight
        } else {
            vmwait<0>();
        }
        __builtin_amdgcn_s_barrier();
        __builtin_amdgcn_sched_barrier(0);
        const short* Ab = As + (ti & 1) * (BM * 64);
        const short* Bb = Bs + (ti & 1) * (BN * 64);
        __builtin_amdgcn_s_setprio(1);
#pragma unroll
        for (int p = 0; p < 2; ++p) {
            bf16x8 a[NI], b[NJ];
#pragma unroll
            for (int i = 0; i < NI; ++i)
                a[i] = *(const bf16x8*)&Ab[p * BM * 32 + (wr + i * 16 + m16) * 32 + q8];
#pragma unroll
            for (int j = 0; j < NJ; ++j)
                b[j] = *(const bf16x8*)&Bb[p * BN * 32 + (wc + j * 16 + m16) * 32 + q8];
#pragma unroll
            for (int i = 0; i < NI; ++i)
#pragma unroll
                for (int j = 0; j < NJ; ++j)
                    acc[i][j] = __builtin_amdgcn_mfma_f32_16x16x32_bf16(a[i], b[j], acc[i][j], 0, 0, 0);
        }
        __builtin_amdgcn_s_setprio(0);
        __builtin_amdgcn_sched_barrier(0);
        __builtin_amdgcn_s_barrier();
    }

#pragma unroll
    for (int i = 0; i < NI; ++i) {
        const int r0 = row0 + wr + i * 16 + q4 * 4;
#pragma unroll
        for (int j = 0; j < NJ; ++j) {
            const int c = col0 + wc + j * 16 + m16;
            const float bv = BIAS ? bias[c] : 0.0f;
            s4v av;
            if (ACCT) av = *(const s4v*)&accT[(long)c * ldat + r0];
#pragma unroll
            for (int t = 0; t < 4; ++t) {
                float x = acc[i][j][t] * alpha + bv;
                if (ACCT) x += bf2f(av[t]);
                const long off = (long)(r0 + t) * ldc + c;
                if (OBF16) ((short*)Cv)[off] = f2bf(x);
                else       ((float*)Cv)[off] = x;
            }
        }
    }
}

// standalone GEMM wrapper (z-batched)
template<int BM, int BN, bool OBF16, bool BIAS, bool ACCT>
__global__ __launch_bounds__(256) void mfma_gemm_k(
    const short* __restrict__ A, int lda, long zsa,
    const short* __restrict__ B, int ldb, long zsb,
    void* __restrict__ Cv, int ldc, long zsc,
    int K, float alpha, const float* __restrict__ bias,
    const short* __restrict__ accT, int ldat)
{
    __shared__ char smem[4 * BM * 64 + 4 * BN * 64];
    const int z = blockIdx.z;
    void* Cz = OBF16 ? (void*)((short*)Cv + (long)z * zsc)
                     : (void*)((float*)Cv + (long)z * zsc);
    gemm_body<BM, BN, OBF16, BIAS, ACCT>(smem,
        A + (long)z * zsa, lda, B + (long)z * zsb, ldb,
        Cz, ldc, K, alpha, bias, accT, ldat, blockIdx.x, blockIdx.y);
}

// merged: QKV projections (z=0 cls full 3C, z=1 reg q,k only) + W1/W2 convert (z=2)
__global__ __launch_bounds__(256) void qkv_conv_k(
    const short* __restrict__ xbf, const short* __restrict__ Wbf,
    short* __restrict__ qkv,
    const float* __restrict__ W1, const float* __restrict__ W2,
    short* __restrict__ W1_bf, short* __restrict__ W2p_bf)
{
    __shared__ char smem[4 * 128 * 64 + 4 * 64 * 64];
    const int z = blockIdx.z;
    if (z == 2) {
        // W1 (1M float4) + W2 packed (1M float4), grid-stride over 768 blocks
        const long stride = 768L * 256;
        const long M = 1024 * 1024;
        for (long i = (long)(blockIdx.y * 48 + blockIdx.x) * 256 + threadIdx.x;
             i < 2 * M; i += stride) {
            if (i < M) {
                float4 v = ((const float4*)W1)[i];
                s4v o;
                o[0] = f2bf(v.x); o[1] = f2bf(v.y);
                o[2] = f2bf(v.z); o[3] = f2bf(v.w);
                ((s4v*)W1_bf)[i] = o;
            } else {
                const long j = i - M;
                float4 v = ((const float4*)W2)[j];
                s4v o;
                o[0] = f2bf(v.x); o[1] = f2bf(v.y);
                o[2] = f2bf(v.z); o[3] = f2bf(v.w);
                const int e = (int)(j << 2);
                const int d = e >> 12, c = e & 4095;
                const long pe = (c < 2048) ? ((long)d * 2048 + c)
                                           : ((long)(1024 + d) * 2048 + (c - 2048));
                ((s4v*)W2p_bf)[pe >> 2] = o;
            }
        }
        return;
    }
    if (z == 1 && blockIdx.x >= 32) return;        // v_reg is dead
    gemm_body<128, 64, true, false, false>(smem,
        xbf + (long)z * PN * PC, PC, Wbf + (long)z * PC3 * PC, PC,
        (void*)(qkv + (long)z * PN * PC3), PC3, PC, 1.0f,
        nullptr, nullptr, 0, blockIdx.x, blockIdx.y);
}

// ---------------- attention row-sum body (64 rows x 512 cols; 3-buf lookahead-2) ----
__device__ __forceinline__ void rowsum_body(char* smem,
    const short* __restrict__ qkv,
    const float* __restrict__ cls_score, const float* __restrict__ fg_score,
    float* __restrict__ l_g, int rb, int h, int zz)
{
    short* Qs  = (short*)smem;                       // 4 × 2048 shorts (16 KB)
    short* Kpb = (short*)(smem + 16384);             // 3 × 4096 shorts (24 KB)
    float* lsum = (float*)(smem + 16384 + 24576);    // [64][2]
    const int tid = threadIdx.x, wave = tid >> 6, lane = tid & 63;
    const int lrow = tid >> 2, lcol = (tid & 3) * 8;
    const int wr = (wave >> 1) * 32, wc = (wave & 1) * 64;
    const int m16 = lane & 15, q4 = lane >> 4, q8 = q4 * 8;
    const int row0 = rb * 64;
    const int side = zz >> 2, chunk = zz & 3;
    const float* sc_g = side ? fg_score : cls_score;
    const short* base = qkv + (long)side * PN * PC3 + h * PD;
    const short* Qg = base + (long)(row0 + lrow) * PC3 + lcol;
    const short* Kg = base + PC + lcol;

    auto stageK = [&](int buf, int step) {   // 2 loads per step
        const int ct = step >> 2, kc = step & 3;
        const long kr = (long)(chunk * 512 + ct * 128 + lrow);
        LDS_DMA(Kg + kr * PC3 + kc * 32, Kpb + buf * 4096 + wave * 512);
        LDS_DMA(Kg + (kr + 64) * PC3 + kc * 32, Kpb + buf * 4096 + 2048 + wave * 512);
    };

#pragma unroll
    for (int kc = 0; kc < 4; ++kc)
        LDS_DMA(Qg + kc * 32, Qs + kc * 2048 + wave * 512);
    stageK(0, 0);
    stageK(1, 1);

    bf16x8 a[2][4];
    float rs[2][4] = {};
    f32x4 acc[2][4];
#pragma unroll
    for (int i = 0; i < 2; ++i)
#pragma unroll
        for (int j = 0; j < 4; ++j) acc[i][j] = (f32x4){0.f, 0.f, 0.f, 0.f};

#pragma unroll
    for (int t = 0; t < 16; ++t) {
        const int ct = t >> 2, kc = t & 3;
        if (t <= 13) {
            stageK((t + 2) % 3, t + 2);
            vmwait<4>();       // stages t+1,t+2 in flight; stage t (and Q) done
        } else if (t == 14) {
            vmwait<2>();
        } else {
            vmwait<0>();
        }
        __builtin_amdgcn_s_barrier();
        __builtin_amdgcn_sched_barrier(0);
        if (t == 0) {
#pragma unroll
            for (int i = 0; i < 2; ++i)
#pragma unroll
                for (int k2 = 0; k2 < 4; ++k2)
                    a[i][k2] = *(const bf16x8*)&Qs[k2 * 2048 + (wr + i * 16 + m16) * 32 + q8];
        }
        bf16x8 b[4];
#pragma unroll
        for (int j = 0; j < 4; ++j)
            b[j] = *(const bf16x8*)&Kpb[(t % 3) * 4096 + (wc + j * 16 + m16) * 32 + q8];
        __builtin_amdgcn_s_setprio(1);
#pragma unroll
        for (int i = 0; i < 2; ++i)
#pragma unroll
            for (int j = 0; j < 4; ++j)
                acc[i][j] = __builtin_amdgcn_mfma_f32_16x16x32_bf16(a[i][kc], b[j], acc[i][j], 0, 0, 0);
        __builtin_amdgcn_s_setprio(0);
        if (kc == 3) {
            const int ctg = chunk * 4 + ct;
#pragma unroll
            for (int j = 0; j < 4; ++j) {
                const float s25 = 25.0f * sc_g[ctg * 128 + wc + j * 16 + m16];
#pragma unroll
                for (int i = 0; i < 2; ++i)
#pragma unroll
                    for (int tt = 0; tt < 4; ++tt)
                        rs[i][tt] += __expf(acc[i][j][tt] * s25);
            }
#pragma unroll
            for (int i = 0; i < 2; ++i)
#pragma unroll
                for (int j = 0; j < 4; ++j) acc[i][j] = (f32x4){0.f, 0.f, 0.f, 0.f};
        }
        __builtin_amdgcn_sched_barrier(0);
        __builtin_amdgcn_s_barrier();
    }

#pragma unroll
    for (int i = 0; i < 2; ++i)
#pragma unroll
        for (int tt = 0; tt < 4; ++tt) {
            float v = rs[i][tt];
            v += __shfl_xor(v, 1, 64); v += __shfl_xor(v, 2, 64);
            v += __shfl_xor(v, 4, 64); v += __shfl_xor(v, 8, 64);
            if (m16 == 0) lsum[(wr + i * 16 + q4 * 4 + tt) * 2 + (wave & 1)] = v;
        }
    __syncthreads();
    if (tid < 64)
        atomicAdd(&l_g[((long)side * PH + h) * PN + row0 + tid],
                  lsum[tid * 2] + lsum[tid * 2 + 1]);
}

// rowsum only (sim_raw moved to the combine launch)
__global__ __launch_bounds__(256) void rowsum_k(
    const short* __restrict__ qkv,
    const float* __restrict__ cls_score, const float* __restrict__ fg_score,
    float* __restrict__ l_g)
{
    __shared__ char smem[49152];
    rowsum_body(smem, qkv, cls_score, fg_score, l_g,
                blockIdx.x, blockIdx.y, blockIdx.z);
}

// ---------------- attention kernel B: per-head attn tiles + sim_raw GEMM (z=8) ----
__global__ __launch_bounds__(256) void attn_combine_k(
    const short* __restrict__ qkv,
    const float* __restrict__ cls_score, const float* __restrict__ fg_score,
    const float* __restrict__ l_g,
    short* __restrict__ attn8,
    const short* __restrict__ Vn, short* __restrict__ sim_raw_bf)
{
    __shared__ char smem[49152];
    if (blockIdx.z == 8) {
        // sim_raw = (Vn @ Vn^T)/H — independent work riding combine's tail
        gemm_body<128, 64, true, false, false>(smem, Vn, PC, Vn, PC,
            (void*)sim_raw_bf, PN, PC, 0.125f, nullptr, nullptr, 0,
            blockIdx.x, blockIdx.y);
        return;
    }
    short* Qp = (short*)smem;            // 4 × [128][32] panels (32 KB)
    short* Kp = (short*)(smem + 32768);  // 4 × [64][32] panels (16 KB)
    const int tid = threadIdx.x, wave = tid >> 6, lane = tid & 63;
    const int lrow = tid >> 2, lcol = (tid & 3) * 8;
    const int wr = (wave >> 1) * 64, wc = (wave & 1) * 32;
    const int m16 = lane & 15, q4 = lane >> 4, q8 = q4 * 8;
    const int col0 = blockIdx.x * 64, row0 = blockIdx.y * 128, h = blockIdx.z;
    const long NN = (long)PN * PN;

    auto stage = [&](int buf, int step) {   // step 0..7: 3 loads
        const int s = step >> 2, kc = step & 3;
        const short* bq = qkv + (long)s * PN * PC3 + h * PD;
        const short* Qg = bq + (long)(row0 + lrow) * PC3 + kc * 32 + lcol;
        LDS_DMA(Qg, Qp + buf * 4096 + wave * 512);
        LDS_DMA(Qg + 64 * (long)PC3, Qp + buf * 4096 + 2048 + wave * 512);
        LDS_DMA(bq + PC + (long)(col0 + lrow) * PC3 + kc * 32 + lcol,
                Kp + buf * 2048 + wave * 512);
    };

    float rl[2][4];
#pragma unroll
    for (int s = 0; s < 2; ++s)
#pragma unroll
        for (int j = 0; j < 4; ++j)
            rl[s][j] = 0.5f / l_g[((long)s * PH + h) * PN + row0 + wr + j * 16 + m16];

    stage(0, 0);
    stage(1, 1);
    stage(2, 2);

    f32x4 acc[2][4], comb[2][4];
#pragma unroll
    for (int i = 0; i < 2; ++i)
#pragma unroll
        for (int j = 0; j < 4; ++j) acc[i][j] = (f32x4){0.f, 0.f, 0.f, 0.f};

#pragma unroll
    for (int t = 0; t < 8; ++t) {
        const int s = t >> 2, kc = t & 3;
        if (t <= 4) {
            stage((t + 3) & 3, t + 3);
            vmwait<9>();       // stages t+1..t+3 in flight; stage t complete
        } else if (t == 5) {
            vmwait<6>();
        } else if (t == 6) {
            vmwait<3>();
        } else {
            vmwait<0>();
        }
        __builtin_amdgcn_s_barrier();
        __builtin_amdgcn_sched_barrier(0);
        bf16x8 qf[4], kf[2];
#pragma unroll
        for (int j = 0; j < 4; ++j)
            qf[j] = *(const bf16x8*)&Qp[(t & 3) * 4096 + (wr + j * 16 + m16) * 32 + q8];
#pragma unroll
        for (int i = 0; i < 2; ++i)
            kf[i] = *(const bf16x8*)&Kp[(t & 3) * 2048 + (wc + i * 16 + m16) * 32 + q8];
        __builtin_amdgcn_s_setprio(1);
#pragma unroll
        for (int i = 0; i < 2; ++i)
#pragma unroll
            for (int j = 0; j < 4; ++j)
                acc[i][j] = __builtin_amdgcn_mfma_f32_16x16x32_bf16(kf[i], qf[j], acc[i][j], 0, 0, 0);
        __builtin_amdgcn_s_setprio(0);
        if (kc == 3) {
            const float* sc_g = s ? fg_score : cls_score;
#pragma unroll
            for (int i = 0; i < 2; ++i) {
                const f32x4 sc4 = *(const f32x4*)&sc_g[col0 + wc + i * 16 + q4 * 4];
#pragma unroll
                for (int j = 0; j < 4; ++j)
#pragma unroll
                    for (int tt = 0; tt < 4; ++tt) {
                        const float e = __expf(acc[i][j][tt] * (25.0f * sc4[tt])) * rl[s][j];
                        comb[i][j][tt] = s ? (comb[i][j][tt] + e) : e;
                        acc[i][j][tt] = 0.f;
                    }
            }
        }
        __builtin_amdgcn_sched_barrier(0);
        __builtin_amdgcn_s_barrier();
    }

#pragma unroll
    for (int j = 0; j < 4; ++j) {
        const long rb = (long)h * NN + (long)(row0 + wr + j * 16 + m16) * PN
                      + col0 + wc + q4 * 4;
#pragma unroll
        for (int i = 0; i < 2; ++i) {
            s4v o;
#pragma unroll
            for (int tt = 0; tt < 4; ++tt) o[tt] = f2bf(comb[i][j][tt]);
            *(s4v*)&attn8[rb + i * 16] = o;
        }
    }
}

// ---------------- reductions ----------------
__device__ __forceinline__ float wave_sum(float v) {
#pragma unroll
    for (int o = 32; o > 0; o >>= 1) v += __shfl_xor(v, o, 64);
    return v;
}
__device__ __forceinline__ float wave_max(float v) {
#pragma unroll
    for (int o = 32; o > 0; o >>= 1) v = fmaxf(v, __shfl_xor(v, o, 64));
    return v;
}
__device__ __forceinline__ float block_sum(float v, float* sm) {
    v = wave_sum(v);
    __syncthreads();
    if ((threadIdx.x & 63) == 0) sm[threadIdx.x >> 6] = v;
    __syncthreads();
    return sm[0] + sm[1] + sm[2] + sm[3];
}
__device__ __forceinline__ float block_max(float v, float* sm) {
    v = wave_max(v);
    __syncthreads();
    if ((threadIdx.x & 63) == 0) sm[threadIdx.x >> 6] = v;
    __syncthreads();
    return fmaxf(fmaxf(sm[0], sm[1]), fmaxf(sm[2], sm[3]));
}

// ---------------- sim_round2 body ----------------
__device__ __forceinline__ void simr2_body(char* smem,
    const short* __restrict__ attn8, const short* __restrict__ Sraw,
    short* __restrict__ Sout, int row)
{
    float* sm = (float*)smem;
    const long NN = (long)PN * PN;
    const long rowoff = (long)row * PN + threadIdx.x * 8;
    float v[8] = {0.f, 0.f, 0.f, 0.f, 0.f, 0.f, 0.f, 0.f};
#pragma unroll
    for (int h = 0; h < PH; ++h) {
        s8v a = *(const s8v*)&attn8[(long)h * NN + rowoff];
#pragma unroll
        for (int j = 0; j < 8; ++j) v[j] += bf2f(a[j]);
    }
    bool keep[8];
    {
        s8v raw = *(const s8v*)&Sraw[rowoff];
#pragma unroll
        for (int j = 0; j < 8; ++j) {
            v[j] *= 0.125f;
            keep[j] = bf2f(raw[j]) > 0.75f;
        }
    }
    float mx = -1e30f;
#pragma unroll
    for (int j = 0; j < 8; ++j) mx = fmaxf(mx, v[j]);
    mx = block_max(mx, sm);
    float sum = 0.f;
#pragma unroll
    for (int j = 0; j < 8; ++j) { v[j] = __expf(v[j] - mx); sum += v[j]; }
    sum = block_sum(sum, sm);
    const float inv = 1.0f / sum;
    float msum = 0.f;
#pragma unroll
    for (int j = 0; j < 8; ++j) { v[j] = keep[j] ? v[j] * inv : 0.f; msum += v[j]; }
    msum = block_sum(msum, sm);
    const float minv = 1.0f / msum;
    s8v o;
#pragma unroll
    for (int j = 0; j < 8; ++j) o[j] = f2bf(v[j] * minv);
    *(s8v*)&Sout[rowoff] = o;
}

// merged: PV GEMM (bid<512) + sim_round2 (bid>=512)
__global__ __launch_bounds__(256) void pv_simr2_k(
    const short* __restrict__ attn8, const short* __restrict__ vT,
    short* __restrict__ trans,
    const short* __restrict__ Sraw, short* __restrict__ Sout)
{
    __shared__ char smem[4 * 64 * 64 + 4 * 64 * 64];   // 32 KB
    const int bid = blockIdx.x;
    if (bid < 512) {
        const int inner = bid & 63, bx = inner & 1, by = inner >> 1, z = bid >> 6;
        gemm_body<64, 64, true, false, false>(smem,
            attn8 + (long)z * PN * PN, PN,
            vT + (long)z * PD * PN, PN,
            (void*)(trans + (long)z * PD), 2 * PC,
            PN, 1.0f, nullptr, nullptr, 0, bx, by);
    } else {
        simr2_body(smem, attn8, Sraw, Sout, bid - 512);
    }
}

// ---------------- fp32 -> bf16 convert: x_cls, x_reg, Wqc, Wqr only ----------------
__global__ __launch_bounds__(256) void f2bf4_k(
    const float* __restrict__ s0, const float* __restrict__ s1,
    const float* __restrict__ s2, const float* __restrict__ s3,
    short* __restrict__ dst)
{
    const int n0 = 512 * 1024, n1 = 512 * 1024, n2 = 768 * 1024;
    const int i = blockIdx.x * 256 + threadIdx.x;
    const float* src;
    int j = i;
    if (j < n0) src = s0;
    else { j -= n0; if (j < n1) src = s1;
    else { j -= n1; if (j < n2) src = s2;
    else { j -= n2; src = s3; } } }
    float4 v = ((const float4*)src)[j];
    s4v o;
    o[0] = f2bf(v.x); o[1] = f2bf(v.y); o[2] = f2bf(v.z); o[3] = f2bf(v.w);
    ((s4v*)dst)[i] = o;
}

// ---------------- transpose body ----------------
__device__ __forceinline__ void tr_body(char* smem,
    const short* __restrict__ src, int sld, short* __restrict__ dst, int dld,
    int bx, int by)
{
    short* tl = (short*)smem;   // [64][72]
    const int r0 = by * 64, c0 = bx * 64;
    const int tr = threadIdx.x >> 2;
    const int tc = (threadIdx.x & 3) * 16;
    const short* sp = src + (long)(r0 + tr) * sld + c0 + tc;
    s8v v0 = *(const s8v*)sp;
    s8v v1 = *(const s8v*)(sp + 8);
    *(s8v*)&tl[tr * 72 + tc] = v0;
    *(s8v*)&tl[tr * 72 + tc + 8] = v1;
    __syncthreads();
    s8v o0, o1;
#pragma unroll
    for (int k = 0; k < 8; ++k) {
        o0[k] = tl[(tc + k) * 72 + tr];
        o1[k] = tl[(tc + 8 + k) * 72 + tr];
    }
    short* dp = dst + (long)(c0 + tr) * dld + r0 + tc;
    *(s8v*)dp = o0;
    *(s8v*)(dp + 8) = o1;
}

// ---------------- norms body ----------------
__device__ __forceinline__ void norms_body(short* __restrict__ qkv,
    short* __restrict__ Vn, short* __restrict__ trans, int n, int which)
{
    const int t = threadIdx.x;
    if (which < 4) {
        short* p = qkv + (long)(which >> 1) * ((long)PN * PC3)
                 + (long)n * PC3 + (which & 1) * PC + t * 4;
        s4v v = *(s4v*)p;
        float f0 = bf2f(v[0]), f1 = bf2f(v[1]), f2 = bf2f(v[2]), f3 = bf2f(v[3]);
        float ss = f0 * f0 + f1 * f1 + f2 * f2 + f3 * f3;
        ss += __shfl_xor(ss, 16, 64); ss += __shfl_xor(ss, 8, 64);
        ss += __shfl_xor(ss, 4, 64);  ss += __shfl_xor(ss, 2, 64);
        ss += __shfl_xor(ss, 1, 64);
        const float rn = rsqrtf(ss);
        s4v o;
        o[0] = f2bf(f0 * rn); o[1] = f2bf(f1 * rn);
        o[2] = f2bf(f2 * rn); o[3] = f2bf(f3 * rn);
        *(s4v*)p = o;
    } else {
        const short* p = qkv + (long)n * PC3 + 2 * PC + t * 4;
        s4v v = *(const s4v*)p;
        float f0 = bf2f(v[0]), f1 = bf2f(v[1]), f2 = bf2f(v[2]), f3 = bf2f(v[3]);
        float ss = f0 * f0 + f1 * f1 + f2 * f2 + f3 * f3;
        ss += __shfl_xor(ss, 16, 64); ss += __shfl_xor(ss, 8, 64);
        ss += __shfl_xor(ss, 4, 64);  ss += __shfl_xor(ss, 2, 64);
        ss += __shfl_xor(ss, 1, 64);
        const float rn = rsqrtf(ss);
        s4v o;
        o[0] = f2bf(f0 * rn); o[1] = f2bf(f1 * rn);
        o[2] = f2bf(f2 * rn); o[3] = f2bf(f3 * rn);
        *(s4v*)(Vn + (long)n * PC + t * 4) = o;
        *(s4v*)(trans + (long)n * (2 * PC) + PC + t * 4) = v;
    }
}

// merged: norms (y<5) + v-transpose (y==5, x<512)
__global__ __launch_bounds__(256) void norms_tr_k(
    short* __restrict__ qkv, short* __restrict__ Vn,
    short* __restrict__ trans, short* __restrict__ vT)
{
    __shared__ char smem[64 * 72 * 2];
    if (blockIdx.y < 5) {
        norms_body(qkv, Vn, trans, blockIdx.x, blockIdx.y);
    } else {
        if (blockIdx.x >= 512) return;
        tr_body(smem, qkv + 2 * PC, PC3, vT, PN,
                blockIdx.x & 15, blockIdx.x >> 4);
    }
}

// ---------------- host ----------------
extern "C" void kernel_launch(void* const* d_in, const int* in_sizes, int n_in,
                              void* d_out, int out_size, void* d_ws, size_t ws_size,
                              hipStream_t stream)
{
    (void)in_sizes; (void)n_in; (void)out_size; (void)ws_size;
    const float* x_cls = (const float*)d_in[0];
    const float* x_reg = (const float*)d_in[1];
    const float* cls_score = (const float*)d_in[2];
    const float* fg_score = (const float*)d_in[3];
    const float* Wqc = (const float*)d_in[4];
    const float* Wqr = (const float*)d_in[5];
    const float* W1 = (const float*)d_in[6];
    const float* b1 = (const float*)d_in[7];
    const float* W2 = (const float*)d_in[8];
    const float* b2 = (const float*)d_in[9];
    float* out = (float*)d_out;

    // ---- workspace (MiB offsets), peak ~156.2 MiB ----
    char* w = (char*)d_ws;
    short* qkv_cls_bf = (short*)(w + ((size_t)0   << 20)); // 12 MiB [N,3C]
    short* qkv_reg_bf = (short*)(w + ((size_t)12  << 20)); // 12 MiB (adjacent)
    short* attn8      = (short*)(w + ((size_t)24  << 20)); // 64 MiB [8][N,N] bf16
    short* sim_bf     = (short*)(w + ((size_t)88  << 20)); // 8 MiB
    short* sim_raw_bf = (short*)(w + ((size_t)104 << 20)); // 8 MiB
    short* Vn         = (short*)(w + ((size_t)112 << 20)); // 4 MiB
    short* vT         = (short*)(w + ((size_t)116 << 20)); // 4 MiB [C,N]
    short* bf_all     = (short*)(w + ((size_t)120 << 20)); // 36 MiB contiguous:
    short* x_cls_bf   = bf_all;                            //  @120, 4 MiB (x_reg @124 adj)
    short* Wqc_bf     = (short*)(w + ((size_t)128 << 20)); //  6 MiB (Wqr @134 adj)
    short* W1_bf      = (short*)(w + ((size_t)140 << 20)); //  8 MiB
    short* W2p_bf     = (short*)(w + ((size_t)148 << 20)); //  8 MiB [2048,2048] packed
    float* l_g        = (float*)(w + ((size_t)156 << 20)); // 128 KiB [2][8][N]
    // overlays (after underlying dead):
    short* trans      = (short*)(w + ((size_t)120 << 20)); // 8 MiB over x_* (post-QKV)
    short* feat       = (short*)(w + ((size_t)24  << 20)); // 8 MiB over attn8[0] (post r2)
    short* UVt        = (short*)(w + ((size_t)32  << 20)); // 8 MiB over attn8[1]

    const long NN = (long)PN * PN;

    // ---- fp32 -> bf16: x_cls, x_reg, Wqc, Wqr (QKV inputs only) ----
    f2bf4_k<<<10240, 256, 0, stream>>>(x_cls, x_reg, Wqc, Wqr, bf_all);

    // ---- QKV projections (z=0,1; reg trimmed) + W1/W2 convert hidden in z=2 ----
    qkv_conv_k<<<dim3(48, 16, 3), 256, 0, stream>>>(
        x_cls_bf, Wqc_bf, qkv_cls_bf, W1, W2, W1_bf, W2p_bf);

    // ---- norms + v transpose (merged) ----
    norms_tr_k<<<dim3(PN, 6), 256, 0, stream>>>(qkv_cls_bf, Vn, trans, vT);

    // ---- attention row sums ----
    hipMemsetAsync(l_g, 0, (size_t)2 * PH * PN * sizeof(float), stream);
    rowsum_k<<<dim3(32, PH, 8), 256, 0, stream>>>(
        qkv_cls_bf, cls_score, fg_score, l_g);

    // ---- per-head attn tiles + sim_raw GEMM riding the tail (z=8) ----
    attn_combine_k<<<dim3(32, 16, 9), 256, 0, stream>>>(
        qkv_cls_bf, cls_score, fg_score, l_g, attn8, Vn, sim_raw_bf);

    // ---- x = attn @ v (z=8) + sim_round2 (merged) ----
    pv_simr2_k<<<2560, 256, 0, stream>>>(attn8, vT, trans, sim_raw_bf, sim_bf);

    // ---- feat = trans @ W1^T + b1 (bf16) ----
    mfma_gemm_k<128, 64, true, true, false><<<dim3(32, 16, 1), 256, 0, stream>>>(
        trans, 2 * PC, 0, W1_bf, 2 * PC, 0, feat, 2 * PC, 0, 2 * PC, 1.0f, b1,
        nullptr, 0);

    // ---- UVt = W2p @ feat^T : rows [0,1024)=U^T, [1024,2048)=V2^T ----
    mfma_gemm_k<128, 64, true, false, false><<<dim3(32, 16, 1), 256, 0, stream>>>(
        W2p_bf, 2 * PC, 0, feat, 2 * PC, 0, UVt, PN, 0, 2 * PC, 1.0f, nullptr,
        nullptr, 0);

    // ---- out = sim_bf @ (U^T)^T + V2 + b2 (64x64 tiles: 512 blocks, 2/CU) ----
    mfma_gemm_k<64, 64, false, true, true><<<dim3(16, 32, 1), 256, 0, stream>>>(
        sim_bf, PN, 0, UVt, PN, 0, out, PC, 0, PN, 1.0f, b2,
        UVt + (long)PC * PN, PN);
}